// Round 7
// baseline (151.526 us; speedup 1.0000x reference)
//
#include <hip/hip_runtime.h>
#include <hip/hip_bf16.h>
#include <stdint.h>

namespace {

constexpr int Bb = 2;
constexpr int Hh = 16;
constexpr int Ss = 2048;
constexpr int Dd = 64;
constexpr int KT = 64;                   // keys per stored tile
constexpr int NT = Ss / KT;              // 32 stored key tiles
constexpr int TILE_BYTES = KT * Dd * 2;  // 8192 B per bf16 tile
constexpr int BH_BYTES = NT * TILE_BYTES;
constexpr size_t KPRE_BYTES = (size_t)Bb * Hh * Ss * Dd * 2;  // 8 MB
constexpr size_t VPRE_OFF = KPRE_BYTES;
constexpr size_t MASK_OFF = 2 * KPRE_BYTES;
constexpr size_t WS_NEED = MASK_OFF + (size_t)Bb * NT * 8;
// split-K partials
constexpr size_t P_OFF  = MASK_OFF + 4096;
constexpr size_t PBYTES = (size_t)Bb * Hh * Ss * Dd * sizeof(float);  // 16.78 MB
constexpr size_t L_OFF  = P_OFF + 2 * PBYTES;
constexpr size_t LBYTES = (size_t)Bb * Hh * Ss * sizeof(float);       // 256 KB
constexpr size_t WS_NEED2 = L_OFF + 2 * LBYTES;                       // ~50.9 MB
constexpr int NIT = 16;                   // iterations (tiles) per split half
constexpr int IT_BYTES = 2 * TILE_BYTES;  // R6 path: 16 KB per tensor per iter

typedef __bf16 bf16x8 __attribute__((ext_vector_type(8)));
typedef float floatx4 __attribute__((ext_vector_type(4)));
typedef short short4v __attribute__((ext_vector_type(4)));
typedef short short8v __attribute__((ext_vector_type(8)));

typedef __attribute__((address_space(1))) const unsigned int guint;
typedef __attribute__((address_space(3))) unsigned int luint;

__device__ __forceinline__ void g2lds16(const void* g, void* l) {
  __builtin_amdgcn_global_load_lds((guint*)g, (luint*)l, 16, 0, 0);
}

__device__ __forceinline__ floatx4 mfma16(short4v a, short4v b, floatx4 c) {
#if __has_builtin(__builtin_amdgcn_mfma_f32_16x16x16bf16_1k)
  return __builtin_amdgcn_mfma_f32_16x16x16bf16_1k(a, b, c, 0, 0, 0);
#else
  floatx4 d;
  __asm__("v_mfma_f32_16x16x16_bf16 %0, %1, %2, %3" : "=v"(d) : "v"(a), "v"(b), "v"(c));
  return d;
#endif
}

__device__ __forceinline__ short bf2s(float x) {
  __bf16 h = (__bf16)x;
  return __builtin_bit_cast(short, h);
}

// ---------------- preprocess (per-tile blocks, LDS transpose for V) --------
// K tiles (8192 B): row=key (64 x 128 B), chunk c (8 d-vals, 16 B) at c^(key&7).
// V tiles (8192 B): row=d (64 x 128 B); chunk (q*2+s2) holds keys
//   {32*s2+4q+i} (8B) and {32*s2+16+4q+i} (8B), stored at (q*2+s2)^(d&7).
// mask -> per-(b,tile) 64-bit ballot bitmask.
__global__ __launch_bounds__(256) void preprocess2(
    const float* __restrict__ K, const float* __restrict__ V,
    const int* __restrict__ mask, uint8_t* __restrict__ ws)
{
  const int tid = threadIdx.x;
  const int kt = blockIdx.x;
  if (blockIdx.y == 32) {  // mask pass
    if (kt >= 16) return;
    const int i = kt * 256 + tid;  // 0..4095
    const int bb = i >> 11, key = i & 2047;
    const unsigned long long bal = __ballot(mask[bb * 2048 + key] != 0);
    if ((key & 63) == 0)
      ((unsigned long long*)(ws + MASK_OFF))[bb * NT + (key >> 6)] = bal;
    return;
  }
  const int bh = blockIdx.y;
  __shared__ float Vsh[64 * 68];

  {
    const int c = tid & 7;
#pragma unroll
    for (int half = 0; half < 2; ++half) {
      const int row = (tid >> 3) + half * 32;
      const float4* src = (const float4*)(K + ((size_t)bh * 2048 + kt * 64 + row) * 64 + c * 8);
      const float4 a = src[0], b2 = src[1];
      bf16x8 pk;
      pk[0] = (__bf16)a.x;  pk[1] = (__bf16)a.y;  pk[2] = (__bf16)a.z;  pk[3] = (__bf16)a.w;
      pk[4] = (__bf16)b2.x; pk[5] = (__bf16)b2.y; pk[6] = (__bf16)b2.z; pk[7] = (__bf16)b2.w;
      uint8_t* dst = ws + (size_t)bh * BH_BYTES + kt * TILE_BYTES + row * 128 + ((c ^ (row & 7)) << 4);
      *(bf16x8*)dst = pk;
    }
  }
#pragma unroll
  for (int i = 0; i < 4; ++i) {
    const int vt = tid + 256 * i;
    const int row = vt >> 4, c4 = vt & 15;
    const float4 v4 = *(const float4*)(V + ((size_t)bh * 2048 + kt * 64 + row) * 64 + c4 * 4);
    *(float4*)&Vsh[row * 68 + c4 * 4] = v4;
  }
  __syncthreads();
  {
    const int c16 = tid & 7;
    const int s2 = c16 & 1, q = c16 >> 1;
    const int k0 = 32 * s2 + 4 * q;
#pragma unroll
    for (int half = 0; half < 2; ++half) {
      const int d = (tid >> 3) + half * 32;
      bf16x8 pv;
#pragma unroll
      for (int j = 0; j < 4; ++j) {
        pv[j]     = (__bf16)Vsh[(k0 + j) * 68 + d];
        pv[4 + j] = (__bf16)Vsh[(k0 + 16 + j) * 68 + d];
      }
      uint8_t* dst = ws + VPRE_OFF + (size_t)bh * BH_BYTES + kt * TILE_BYTES + d * 128 + ((c16 ^ (d & 7)) << 4);
      *(bf16x8*)dst = pv;
    }
  }
}

// -10000 * log2(e): reference's masked_fill value, in exp2 domain.
#define NEGM (-14426.950408889634f)

// ---------------- split-K fused attention -----------------------------------
// grid (32 bh, 16 qblk, 2 half). Each block: 128 q-rows x 1024 keys.
// Mask enters as the QK^T MFMA C-initializer (0 / NEGM per key); masked
// scores <= -14000 so exp2 underflows to exactly 0 — no cndmask on p.
// Unnormalized O^T and per-row l go to ws; combine() finishes.
__global__ __launch_bounds__(256, 4) void attn_fused5(
    const float* __restrict__ Q, uint8_t* __restrict__ ws)
{
  const int tid  = threadIdx.x;
  const int wave = tid >> 6;
  const int lane = tid & 63;
  const int ln   = lane & 15;
  const int quad = lane >> 4;

  const int bh   = blockIdx.x;   // 0..31
  const int qblk = blockIdx.y;   // 0..15
  const int half = blockIdx.z;   // 0..1
  const int b    = bh >> 4;

  const float* Qb = Q + (size_t)bh * Ss * Dd;
  const uint8_t* Kpre = ws + (size_t)bh * BH_BYTES + half * NIT * TILE_BYTES;
  const uint8_t* Vpre = ws + VPRE_OFF + (size_t)bh * BH_BYTES + half * NIT * TILE_BYTES;
  const unsigned long long* Mbits =
      (const unsigned long long*)(ws + MASK_OFF) + b * NT + half * NIT;
  float* Pst = (float*)(ws + P_OFF + half * PBYTES) + (size_t)bh * Ss * Dd;
  float* Lst = (float*)(ws + L_OFF + half * LBYTES) + (size_t)bh * Ss;

  __shared__ __align__(16) __bf16 Klds[2][KT * Dd];   // 2 x 8 KB
  __shared__ __align__(16) __bf16 Vlds[2][KT * Dd];   // 2 x 8 KB

  const int q0A = qblk * 128 + wave * 32;
  const int q0B = q0A + 16;

  const float QS = 0.125f * 1.44269504088896340736f;
  bf16x8 aqA0, aqA1, aqB0, aqB1;
  {
    const float* qpA = Qb + (size_t)(q0A + ln) * Dd + quad * 8;
    const float* qpB = Qb + (size_t)(q0B + ln) * Dd + quad * 8;
#pragma unroll
    for (int j = 0; j < 8; ++j) {
      aqA0[j] = (__bf16)(qpA[j] * QS);
      aqA1[j] = (__bf16)(qpA[32 + j] * QS);
      aqB0[j] = (__bf16)(qpB[j] * QS);
      aqB1[j] = (__bf16)(qpB[32 + j] * QS);
    }
  }

  floatx4 oA[4], oB[4];
  floatx4 laccA = (floatx4){0.f, 0.f, 0.f, 0.f};
  floatx4 laccB = (floatx4){0.f, 0.f, 0.f, 0.f};
#pragma unroll
  for (int nd = 0; nd < 4; ++nd) {
    oA[nd] = (floatx4){0.f, 0.f, 0.f, 0.f};
    oB[nd] = (floatx4){0.f, 0.f, 0.f, 0.f};
  }

  const int swz0 = (quad ^ (ln & 7)) << 4;
  const int swz1 = ((quad + 4) ^ (ln & 7)) << 4;
  const int soff0 = wave * 2048 + lane * 16;
  const int soff1 = soff0 + 1024;

  // prologue: stage tile 0 into buffer 0
  g2lds16(Kpre + soff0, (uint8_t*)Klds[0] + soff0);
  g2lds16(Vpre + soff0, (uint8_t*)Vlds[0] + soff0);
  g2lds16(Kpre + soff1, (uint8_t*)Klds[0] + soff1);
  g2lds16(Vpre + soff1, (uint8_t*)Vlds[0] + soff1);

  for (int kt = 0; kt < NIT; ++kt) {
    const int cur = kt & 1;
    __syncthreads();  // closes prev-iter reads + drains this buf's g2lds

    if (kt + 1 < NIT) {
      const uint8_t* kg = Kpre + (kt + 1) * TILE_BYTES;
      const uint8_t* vg = Vpre + (kt + 1) * TILE_BYTES;
      uint8_t* kl = (uint8_t*)Klds[cur ^ 1];
      uint8_t* vl = (uint8_t*)Vlds[cur ^ 1];
      g2lds16(kg + soff0, kl + soff0);
      g2lds16(vg + soff0, vl + soff0);
      g2lds16(kg + soff1, kl + soff1);
      g2lds16(vg + soff1, vl + soff1);
    }

    // per-key mask bias, shared by both q-streams: keys 16*sub + quad*4 + r
    const unsigned long long mb = Mbits[kt];
    floatx4 biasC[4];
#pragma unroll
    for (int sub = 0; sub < 4; ++sub) {
      const uint32_t bits = (uint32_t)(mb >> (sub * 16 + quad * 4));
#pragma unroll
      for (int r = 0; r < 4; ++r)
        biasC[sub][r] = ((bits >> r) & 1) ? NEGM : 0.f;
    }

    // ---- S^T = K.Q^T + bias ----
    floatx4 sA[4], sB[4];
#pragma unroll
    for (int sub = 0; sub < 4; ++sub) {
      const uint8_t* krow = (const uint8_t*)Klds[cur] + (sub * 16 + ln) * 128;
      const bf16x8 bk0 = *(const bf16x8*)(krow + swz0);
      const bf16x8 bk1 = *(const bf16x8*)(krow + swz1);
      floatx4 cA = biasC[sub];
      cA = __builtin_amdgcn_mfma_f32_16x16x32_bf16(bk0, aqA0, cA, 0, 0, 0);
      cA = __builtin_amdgcn_mfma_f32_16x16x32_bf16(bk1, aqA1, cA, 0, 0, 0);
      sA[sub] = cA;
      floatx4 cB = biasC[sub];
      cB = __builtin_amdgcn_mfma_f32_16x16x32_bf16(bk0, aqB0, cB, 0, 0, 0);
      cB = __builtin_amdgcn_mfma_f32_16x16x32_bf16(bk1, aqB1, cB, 0, 0, 0);
      sB[sub] = cB;
    }

    // ---- exp2 (masked -> exact 0 via underflow) + partial l + pack ----
    short4v bpA[4], bpB[4];
#pragma unroll
    for (int sub = 0; sub < 4; ++sub) {
#pragma unroll
      for (int r = 0; r < 4; ++r) {
        const float pA = __builtin_amdgcn_exp2f(sA[sub][r]);
        const float pB = __builtin_amdgcn_exp2f(sB[sub][r]);
        laccA[r] += pA;
        laccB[r] += pB;
        bpA[sub][r] = bf2s(pA);
        bpB[sub][r] = bf2s(pB);
      }
    }

    // ---- O^T += V^T . P^T ----
#pragma unroll
    for (int nd = 0; nd < 4; ++nd) {
      const uint8_t* vrow = (const uint8_t*)Vlds[cur] + (nd * 16 + ln) * 128;
#pragma unroll
      for (int s2 = 0; s2 < 2; ++s2) {
        const short8v w = *(const short8v*)(vrow + (((quad * 2 + s2) ^ (ln & 7)) << 4));
        const short4v vlo = __builtin_shufflevector(w, w, 0, 1, 2, 3);
        const short4v vhi = __builtin_shufflevector(w, w, 4, 5, 6, 7);
        oA[nd] = mfma16(vlo, bpA[2 * s2], oA[nd]);
        oA[nd] = mfma16(vhi, bpA[2 * s2 + 1], oA[nd]);
        oB[nd] = mfma16(vlo, bpB[2 * s2], oB[nd]);
        oB[nd] = mfma16(vhi, bpB[2 * s2 + 1], oB[nd]);
      }
    }
  }

  // ---- epilogue: write UNNORMALIZED O and per-row l partials ----
  float lA = (laccA[0] + laccA[1]) + (laccA[2] + laccA[3]);
  float lB = (laccB[0] + laccB[1]) + (laccB[2] + laccB[3]);
  lA += __shfl_xor(lA, 16); lA += __shfl_xor(lA, 32);
  lB += __shfl_xor(lB, 16); lB += __shfl_xor(lB, 32);
  if (quad == 0) {
    Lst[q0A + ln] = lA;
    Lst[q0B + ln] = lB;
  }
#pragma unroll
  for (int nd = 0; nd < 4; ++nd) {
    float4 wv;
    wv.x = oA[nd][0]; wv.y = oA[nd][1]; wv.z = oA[nd][2]; wv.w = oA[nd][3];
    *(float4*)(Pst + (size_t)(q0A + ln) * Dd + nd * 16 + quad * 4) = wv;
    wv.x = oB[nd][0]; wv.y = oB[nd][1]; wv.z = oB[nd][2]; wv.w = oB[nd][3];
    *(float4*)(Pst + (size_t)(q0B + ln) * Dd + nd * 16 + quad * 4) = wv;
  }
}

// ---------------- combine: O = (P0+P1)/(l0+l1) ----------------
__global__ __launch_bounds__(256) void combine(const uint8_t* __restrict__ ws,
                                               float* __restrict__ Out)
{
  const int t = blockIdx.x * 256 + threadIdx.x;  // float4 index, 0..1048575
  const float4 p0 = ((const float4*)(ws + P_OFF))[t];
  const float4 p1 = ((const float4*)(ws + P_OFF + PBYTES))[t];
  const int qi = t >> 4;  // q-row = 4t/64
  const float l0 = ((const float*)(ws + L_OFF))[qi];
  const float l1 = ((const float*)(ws + L_OFF + LBYTES))[qi];
  const float inv = 1.0f / (l0 + l1);
  float4 o;
  o.x = (p0.x + p1.x) * inv;
  o.y = (p0.y + p1.y) * inv;
  o.z = (p0.z + p1.z) * inv;
  o.w = (p0.w + p1.w) * inv;
  ((float4*)Out)[t] = o;
}

// ---------------- R6 path (no-split), used if ws < WS_NEED2 ----------------
__global__ __launch_bounds__(256, 2) void attn_fused4(
    const float* __restrict__ Q, const uint8_t* __restrict__ ws,
    float* __restrict__ Out)
{
  const int tid  = threadIdx.x;
  const int wave = tid >> 6;
  const int lane = tid & 63;
  const int ln   = lane & 15;
  const int quad = lane >> 4;
  const int bh   = blockIdx.x;
  const int qblk = blockIdx.y;
  const int b    = bh >> 4;

  const float* Qb = Q + (size_t)bh * Ss * Dd;
  float*       Ob = Out + (size_t)bh * Ss * Dd;
  const uint8_t* Kpre = ws + (size_t)bh * BH_BYTES;
  const uint8_t* Vpre = ws + VPRE_OFF + (size_t)bh * BH_BYTES;
  const unsigned long long* Mbits = (const unsigned long long*)(ws + MASK_OFF) + b * NT;

  __shared__ __align__(16) __bf16 Klds[2][128 * Dd];
  __shared__ __align__(16) __bf16 Vlds[2][128 * Dd];

  const int q0A = qblk * 128 + wave * 32;
  const int q0B = q0A + 16;
  const float QS = 0.125f * 1.44269504088896340736f;
  bf16x8 aqA0, aqA1, aqB0, aqB1;
  {
    const float* qpA = Qb + (size_t)(q0A + ln) * Dd + quad * 8;
    const float* qpB = Qb + (size_t)(q0B + ln) * Dd + quad * 8;
#pragma unroll
    for (int j = 0; j < 8; ++j) {
      aqA0[j] = (__bf16)(qpA[j] * QS);
      aqA1[j] = (__bf16)(qpA[32 + j] * QS);
      aqB0[j] = (__bf16)(qpB[j] * QS);
      aqB1[j] = (__bf16)(qpB[32 + j] * QS);
    }
  }
  floatx4 oA[4], oB[4];
  floatx4 laccA = (floatx4){0.f, 0.f, 0.f, 0.f};
  floatx4 laccB = (floatx4){0.f, 0.f, 0.f, 0.f};
#pragma unroll
  for (int nd = 0; nd < 4; ++nd) {
    oA[nd] = (floatx4){0.f, 0.f, 0.f, 0.f};
    oB[nd] = (floatx4){0.f, 0.f, 0.f, 0.f};
  }
  const int swz0 = (quad ^ (ln & 7)) << 4;
  const int swz1 = ((quad + 4) ^ (ln & 7)) << 4;
  const int soff = wave * 4096 + lane * 16;
#pragma unroll
  for (int i = 0; i < 4; ++i) {
    g2lds16(Kpre + soff + i * 1024, (uint8_t*)Klds[0] + soff + i * 1024);
    g2lds16(Vpre + soff + i * 1024, (uint8_t*)Vlds[0] + soff + i * 1024);
  }
  for (int kt2 = 0; kt2 < 16; ++kt2) {
    const int cur = kt2 & 1;
    __syncthreads();
    if (kt2 + 1 < 16) {
      const uint8_t* kg = Kpre + (kt2 + 1) * IT_BYTES;
      const uint8_t* vg = Vpre + (kt2 + 1) * IT_BYTES;
      uint8_t* kl = (uint8_t*)Klds[cur ^ 1];
      uint8_t* vl = (uint8_t*)Vlds[cur ^ 1];
#pragma unroll
      for (int i = 0; i < 4; ++i) {
        g2lds16(kg + soff + i * 1024, kl + soff + i * 1024);
        g2lds16(vg + soff + i * 1024, vl + soff + i * 1024);
      }
    }
    const unsigned long long mb0 = Mbits[2 * kt2];
    const unsigned long long mb1 = Mbits[2 * kt2 + 1];
    floatx4 sA[8], sB[8];
#pragma unroll
    for (int sub = 0; sub < 8; ++sub) {
      const uint8_t* krow = (const uint8_t*)Klds[cur] + (sub >> 2) * 8192 + ((sub & 3) * 16 + ln) * 128;
      const bf16x8 bk0 = *(const bf16x8*)(krow + swz0);
      const bf16x8 bk1 = *(const bf16x8*)(krow + swz1);
      floatx4 cA = (floatx4){0.f, 0.f, 0.f, 0.f};
      cA = __builtin_amdgcn_mfma_f32_16x16x32_bf16(bk0, aqA0, cA, 0, 0, 0);
      cA = __builtin_amdgcn_mfma_f32_16x16x32_bf16(bk1, aqA1, cA, 0, 0, 0);
      sA[sub] = cA;
      floatx4 cB = (floatx4){0.f, 0.f, 0.f, 0.f};
      cB = __builtin_amdgcn_mfma_f32_16x16x32_bf16(bk0, aqB0, cB, 0, 0, 0);
      cB = __builtin_amdgcn_mfma_f32_16x16x32_bf16(bk1, aqB1, cB, 0, 0, 0);
      sB[sub] = cB;
    }
    short4v bpA[8], bpB[8];
#pragma unroll
    for (int sub = 0; sub < 8; ++sub) {
      const unsigned long long mbx = (sub & 4) ? mb1 : mb0;
      const uint32_t bits = (uint32_t)(mbx >> ((sub & 3) * 16 + quad * 4));
#pragma unroll
      for (int r = 0; r < 4; ++r) {
        const bool msk = (bits >> r) & 1;
        float pA = __builtin_amdgcn_exp2f(sA[sub][r]);
        float pB = __builtin_amdgcn_exp2f(sB[sub][r]);
        pA = msk ? 0.f : pA;
        pB = msk ? 0.f : pB;
        laccA[r] += pA;
        laccB[r] += pB;
        bpA[sub][r] = bf2s(pA);
        bpB[sub][r] = bf2s(pB);
      }
    }
#pragma unroll
    for (int nd = 0; nd < 4; ++nd) {
#pragma unroll
      for (int T = 0; T < 2; ++T) {
        const uint8_t* vrow = (const uint8_t*)Vlds[cur] + T * 8192 + (nd * 16 + ln) * 128;
#pragma unroll
        for (int s2 = 0; s2 < 2; ++s2) {
          const short8v w = *(const short8v*)(vrow + (((quad * 2 + s2) ^ (ln & 7)) << 4));
          const short4v vlo = __builtin_shufflevector(w, w, 0, 1, 2, 3);
          const short4v vhi = __builtin_shufflevector(w, w, 4, 5, 6, 7);
          const int sub0 = T * 4 + 2 * s2;
          oA[nd] = mfma16(vlo, bpA[sub0], oA[nd]);
          oA[nd] = mfma16(vhi, bpA[sub0 + 1], oA[nd]);
          oB[nd] = mfma16(vlo, bpB[sub0], oB[nd]);
          oB[nd] = mfma16(vhi, bpB[sub0 + 1], oB[nd]);
        }
      }
    }
  }
  float lA = (laccA[0] + laccA[1]) + (laccA[2] + laccA[3]);
  float lB = (laccB[0] + laccB[1]) + (laccB[2] + laccB[3]);
  lA += __shfl_xor(lA, 16); lA += __shfl_xor(lA, 32);
  lB += __shfl_xor(lB, 16); lB += __shfl_xor(lB, 32);
  const float iA = 1.0f / lA, iB = 1.0f / lB;
#pragma unroll
  for (int nd = 0; nd < 4; ++nd) {
    float4 wv;
    wv.x = oA[nd][0] * iA; wv.y = oA[nd][1] * iA;
    wv.z = oA[nd][2] * iA; wv.w = oA[nd][3] * iA;
    *(float4*)(Ob + (size_t)(q0A + ln) * Dd + nd * 16 + quad * 4) = wv;
    wv.x = oB[nd][0] * iB; wv.y = oB[nd][1] * iB;
    wv.z = oB[nd][2] * iB; wv.w = oB[nd][3] * iB;
    *(float4*)(Ob + (size_t)(q0B + ln) * Dd + nd * 16 + quad * 4) = wv;
  }
}

}  // namespace

extern "C" void kernel_launch(void* const* d_in, const int* in_sizes, int n_in,
                              void* d_out, int out_size, void* d_ws, size_t ws_size,
                              hipStream_t stream) {
  const float* Q   = (const float*)d_in[0];
  const float* K   = (const float*)d_in[1];
  const float* V   = (const float*)d_in[2];
  const int*  mask = (const int*)d_in[3];
  float* Out = (float*)d_out;

  if (ws_size >= WS_NEED2) {
    preprocess2<<<dim3(32, 33), 256, 0, stream>>>(K, V, mask, (uint8_t*)d_ws);
    attn_fused5<<<dim3(Bb * Hh, Ss / 128, 2), 256, 0, stream>>>(Q, (uint8_t*)d_ws);
    combine<<<(Bb * Hh * Ss * Dd / 4 + 255) / 256, 256, 0, stream>>>((const uint8_t*)d_ws, Out);
  } else if (ws_size >= WS_NEED) {
    preprocess2<<<dim3(32, 33), 256, 0, stream>>>(K, V, mask, (uint8_t*)d_ws);
    attn_fused4<<<dim3(Bb * Hh, Ss / 128), 256, 0, stream>>>(Q, (const uint8_t*)d_ws, Out);
  }
}

// Round 8
// 135.941 us; speedup vs baseline: 1.1146x; 1.1146x over previous
//
#include <hip/hip_runtime.h>
#include <hip/hip_bf16.h>
#include <stdint.h>

namespace {

constexpr int Bb = 2;
constexpr int Hh = 16;
constexpr int Ss = 2048;
constexpr int Dd = 64;
constexpr int KT = 64;                   // keys per stored tile
constexpr int NT = Ss / KT;              // 32 stored key tiles
constexpr int TILE_BYTES = KT * Dd * 2;  // 8192 B per bf16 tile
constexpr int BH_BYTES = NT * TILE_BYTES;
constexpr size_t KPRE_BYTES = (size_t)Bb * Hh * Ss * Dd * 2;  // 8 MB
constexpr size_t VPRE_OFF = KPRE_BYTES;
constexpr size_t MASK_OFF = 2 * KPRE_BYTES;
constexpr size_t WS_NEED = MASK_OFF + (size_t)Bb * NT * 8;
constexpr int NIT = 16;                   // 128-key iterations
constexpr int IT_BYTES = 2 * TILE_BYTES;  // 16 KB per tensor per iter

typedef __bf16 bf16x8 __attribute__((ext_vector_type(8)));
typedef float floatx4 __attribute__((ext_vector_type(4)));

typedef __attribute__((address_space(1))) const unsigned int guint;
typedef __attribute__((address_space(3))) unsigned int luint;

__device__ __forceinline__ void g2lds16(const void* g, void* l) {
  __builtin_amdgcn_global_load_lds((guint*)g, (luint*)l, 16, 0, 0);
}

// ---------------- preprocess3 ----------------
// ws layout identical to R5-R7 (validated):
// K tiles (8192 B): row=key (64 x 128 B), chunk c (8 d-vals, 16 B) at c^(key&7).
// V tiles (8192 B): row=d (64 x 128 B); chunk (q*2+s2) holds keys
//   {32*s2+4q+i} (8B) and {32*s2+16+4q+i} (8B), stored at (q*2+s2)^(d&7).
// mask -> per-(b,tile) 64-bit ballot bitmask.
// Grid (32 kt, 32 bh, 2): z=0 K-stream blocks (no barrier; bh==0,kt<16 also
// do the mask ballots), z=1 V-transpose blocks (LDS round-trip).
__global__ __launch_bounds__(256) void preprocess3(
    const float* __restrict__ K, const float* __restrict__ V,
    const int* __restrict__ mask, uint8_t* __restrict__ ws)
{
  const int tid = threadIdx.x;
  const int kt = blockIdx.x;
  const int bh = blockIdx.y;

  if (blockIdx.z == 0) {
    // ---- K: convert + swizzled store (both sides contiguous per wave) ----
    const int c = tid & 7;
#pragma unroll
    for (int half = 0; half < 2; ++half) {
      const int row = (tid >> 3) + half * 32;
      const float4* src = (const float4*)(K + ((size_t)bh * 2048 + kt * 64 + row) * 64 + c * 8);
      const float4 a = src[0], b2 = src[1];
      bf16x8 pk;
      pk[0] = (__bf16)a.x;  pk[1] = (__bf16)a.y;  pk[2] = (__bf16)a.z;  pk[3] = (__bf16)a.w;
      pk[4] = (__bf16)b2.x; pk[5] = (__bf16)b2.y; pk[6] = (__bf16)b2.z; pk[7] = (__bf16)b2.w;
      uint8_t* dst = ws + (size_t)bh * BH_BYTES + kt * TILE_BYTES + row * 128 + ((c ^ (row & 7)) << 4);
      *(bf16x8*)dst = pk;
    }
    if (bh == 0 && kt < 16) {  // mask ballots: 16 blocks cover Bb*Ss = 4096
      const int i = kt * 256 + tid;
      const int bb = i >> 11, key = i & 2047;
      const unsigned long long bal = __ballot(mask[bb * 2048 + key] != 0);
      if ((key & 63) == 0)
        ((unsigned long long*)(ws + MASK_OFF))[bb * NT + (key >> 6)] = bal;
    }
    return;
  }

  // ---- V: coalesced load -> LDS -> transposed swizzled store ----
  __shared__ float Vsh[64 * 68];
#pragma unroll
  for (int i = 0; i < 4; ++i) {
    const int vt = tid + 256 * i;
    const int row = vt >> 4, c4 = vt & 15;
    const float4 v4 = *(const float4*)(V + ((size_t)bh * 2048 + kt * 64 + row) * 64 + c4 * 4);
    *(float4*)&Vsh[row * 68 + c4 * 4] = v4;
  }
  __syncthreads();
  {
    const int c16 = tid & 7;
    const int s2 = c16 & 1, q = c16 >> 1;
    const int k0 = 32 * s2 + 4 * q;
#pragma unroll
    for (int half = 0; half < 2; ++half) {
      const int d = (tid >> 3) + half * 32;
      bf16x8 pv;
#pragma unroll
      for (int j = 0; j < 4; ++j) {
        pv[j]     = (__bf16)Vsh[(k0 + j) * 68 + d];
        pv[4 + j] = (__bf16)Vsh[(k0 + 16 + j) * 68 + d];
      }
      uint8_t* dst = ws + VPRE_OFF + (size_t)bh * BH_BYTES + kt * TILE_BYTES + d * 128 + ((c16 ^ (d & 7)) << 4);
      *(bf16x8*)dst = pv;
    }
  }
}

// -10000 * log2(e): reference's masked_fill value, in exp2 domain.
#define NEGM (-14426.950408889634f)

// ---------------- fused attention (S^T, KT=128, mask-as-C-bias, PV K=32) ----
// Wave: 32 q-rows (2 q-tiles). lane holds scores for q=(lane&15),
// keys 16*sub+quad*4+r (C-layout of S^T = K.Q^T).
// PV: the V-tile short8 chunk (quad*2+s2)^(ln&7) of row d enumerates keys
// {32s2+4*quad+i, 32s2+16+4*quad+i} == the K=32 A-frag k-order under a
// permutation pi; packing subtile pair (2s2,2s2+1) p's into one bf16x8 makes
// B agree with pi -> one mfma_16x16x32 per (nd,T,s2) per stream.
__global__ __launch_bounds__(256, 2) void attn_fused6(
    const float* __restrict__ Q, const uint8_t* __restrict__ ws,
    float* __restrict__ Out)
{
  const int tid  = threadIdx.x;
  const int wave = tid >> 6;
  const int lane = tid & 63;
  const int ln   = lane & 15;
  const int quad = lane >> 4;

  const int bh   = blockIdx.x;  // 0..31 (same bh -> same XCD for L2 reuse)
  const int qblk = blockIdx.y;  // 0..15
  const int b    = bh >> 4;

  const float* Qb = Q + (size_t)bh * Ss * Dd;
  float*       Ob = Out + (size_t)bh * Ss * Dd;
  const uint8_t* Kpre = ws + (size_t)bh * BH_BYTES;
  const uint8_t* Vpre = ws + VPRE_OFF + (size_t)bh * BH_BYTES;
  const unsigned long long* Mbits = (const unsigned long long*)(ws + MASK_OFF) + b * NT;

  __shared__ __align__(16) __bf16 Klds[2][128 * Dd];   // 2 x 16 KB
  __shared__ __align__(16) __bf16 Vlds[2][128 * Dd];   // 2 x 16 KB

  const int q0A = qblk * 128 + wave * 32;
  const int q0B = q0A + 16;

  // Q B-frags, pre-scaled by 1/8*log2(e). B[k=quad*8+j][n=ln] = Qs[q][d].
  const float QS = 0.125f * 1.44269504088896340736f;
  bf16x8 aqA0, aqA1, aqB0, aqB1;
  {
    const float* qpA = Qb + (size_t)(q0A + ln) * Dd + quad * 8;
    const float* qpB = Qb + (size_t)(q0B + ln) * Dd + quad * 8;
#pragma unroll
    for (int j = 0; j < 8; ++j) {
      aqA0[j] = (__bf16)(qpA[j] * QS);
      aqA1[j] = (__bf16)(qpA[32 + j] * QS);
      aqB0[j] = (__bf16)(qpB[j] * QS);
      aqB1[j] = (__bf16)(qpB[32 + j] * QS);
    }
  }

  floatx4 oA[4], oB[4];    // O^T C-layout: d = nd*16+quad*4+r, q = ln
  floatx4 laccA = (floatx4){0.f, 0.f, 0.f, 0.f};
  floatx4 laccB = (floatx4){0.f, 0.f, 0.f, 0.f};
#pragma unroll
  for (int nd = 0; nd < 4; ++nd) {
    oA[nd] = (floatx4){0.f, 0.f, 0.f, 0.f};
    oB[nd] = (floatx4){0.f, 0.f, 0.f, 0.f};
  }

  const int swz0 = (quad ^ (ln & 7)) << 4;
  const int swz1 = ((quad + 4) ^ (ln & 7)) << 4;
  const int soff = wave * 4096 + lane * 16;

  // prologue: stage iter 0 into buffer 0
#pragma unroll
  for (int i = 0; i < 4; ++i) {
    g2lds16(Kpre + soff + i * 1024, (uint8_t*)Klds[0] + soff + i * 1024);
    g2lds16(Vpre + soff + i * 1024, (uint8_t*)Vlds[0] + soff + i * 1024);
  }

  for (int kt2 = 0; kt2 < NIT; ++kt2) {
    const int cur = kt2 & 1;
    __syncthreads();  // closes prev-iter reads + drains this buf's g2lds

    if (kt2 + 1 < NIT) {
      const uint8_t* kg = Kpre + (kt2 + 1) * IT_BYTES;
      const uint8_t* vg = Vpre + (kt2 + 1) * IT_BYTES;
      uint8_t* kl = (uint8_t*)Klds[cur ^ 1];
      uint8_t* vl = (uint8_t*)Vlds[cur ^ 1];
#pragma unroll
      for (int i = 0; i < 4; ++i) {
        g2lds16(kg + soff + i * 1024, kl + soff + i * 1024);
        g2lds16(vg + soff + i * 1024, vl + soff + i * 1024);
      }
    }

    // per-key mask bias (shared by both q-streams): key = 16*sub+quad*4+r
    const unsigned long long mb0 = Mbits[2 * kt2];
    const unsigned long long mb1 = Mbits[2 * kt2 + 1];
    floatx4 biasC[8];
#pragma unroll
    for (int sub = 0; sub < 8; ++sub) {
      const unsigned long long mbx = (sub & 4) ? mb1 : mb0;
      const uint32_t bits = (uint32_t)(mbx >> ((sub & 3) * 16 + quad * 4));
#pragma unroll
      for (int r = 0; r < 4; ++r)
        biasC[sub][r] = ((bits >> r) & 1) ? NEGM : 0.f;
    }

    // ---- S^T = K.Q^T + bias : 8 subtiles of 16 keys ----
    floatx4 sA[8], sB[8];
#pragma unroll
    for (int sub = 0; sub < 8; ++sub) {
      const uint8_t* krow = (const uint8_t*)Klds[cur] + (sub >> 2) * 8192 + ((sub & 3) * 16 + ln) * 128;
      const bf16x8 bk0 = *(const bf16x8*)(krow + swz0);
      const bf16x8 bk1 = *(const bf16x8*)(krow + swz1);
      floatx4 cA = biasC[sub];
      cA = __builtin_amdgcn_mfma_f32_16x16x32_bf16(bk0, aqA0, cA, 0, 0, 0);
      cA = __builtin_amdgcn_mfma_f32_16x16x32_bf16(bk1, aqA1, cA, 0, 0, 0);
      sA[sub] = cA;
      floatx4 cB = biasC[sub];
      cB = __builtin_amdgcn_mfma_f32_16x16x32_bf16(bk0, aqB0, cB, 0, 0, 0);
      cB = __builtin_amdgcn_mfma_f32_16x16x32_bf16(bk1, aqB1, cB, 0, 0, 0);
      sB[sub] = cB;
    }

    // ---- exp2 (masked -> exact 0 via underflow) + partial l + pack ----
    // pack subtile pair (sub, sub^1) into one K=32 B-frag: bp[pair][u*4+r]
    bf16x8 bpA[4], bpB[4];
#pragma unroll
    for (int sub = 0; sub < 8; ++sub) {
      const int pair = sub >> 1, u = sub & 1;
#pragma unroll
      for (int r = 0; r < 4; ++r) {
        const float pA = __builtin_amdgcn_exp2f(sA[sub][r]);
        const float pB = __builtin_amdgcn_exp2f(sB[sub][r]);
        laccA[r] += pA;
        laccB[r] += pB;
        bpA[pair][u * 4 + r] = (__bf16)pA;
        bpB[pair][u * 4 + r] = (__bf16)pB;
      }
    }

    // ---- O^T += V^T . P^T at K=32: one mfma per (nd,T,s2) per stream ----
#pragma unroll
    for (int nd = 0; nd < 4; ++nd) {
#pragma unroll
      for (int T = 0; T < 2; ++T) {
        const uint8_t* vrow = (const uint8_t*)Vlds[cur] + T * 8192 + (nd * 16 + ln) * 128;
#pragma unroll
        for (int s2 = 0; s2 < 2; ++s2) {
          const bf16x8 w = *(const bf16x8*)(vrow + (((quad * 2 + s2) ^ (ln & 7)) << 4));
          const int pair = T * 2 + s2;
          oA[nd] = __builtin_amdgcn_mfma_f32_16x16x32_bf16(w, bpA[pair], oA[nd], 0, 0, 0);
          oB[nd] = __builtin_amdgcn_mfma_f32_16x16x32_bf16(w, bpB[pair], oB[nd], 0, 0, 0);
        }
      }
    }
  }

  // ---- epilogue: reduce l across quads, normalize, store ----
  float lA = (laccA[0] + laccA[1]) + (laccA[2] + laccA[3]);
  float lB = (laccB[0] + laccB[1]) + (laccB[2] + laccB[3]);
  lA += __shfl_xor(lA, 16); lA += __shfl_xor(lA, 32);
  lB += __shfl_xor(lB, 16); lB += __shfl_xor(lB, 32);
  const float iA = 1.0f / lA, iB = 1.0f / lB;
#pragma unroll
  for (int nd = 0; nd < 4; ++nd) {
    float4 wv;
    wv.x = oA[nd][0] * iA; wv.y = oA[nd][1] * iA;
    wv.z = oA[nd][2] * iA; wv.w = oA[nd][3] * iA;
    *(float4*)(Ob + (size_t)(q0A + ln) * Dd + nd * 16 + quad * 4) = wv;
    wv.x = oB[nd][0] * iB; wv.y = oB[nd][1] * iB;
    wv.z = oB[nd][2] * iB; wv.w = oB[nd][3] * iB;
    *(float4*)(Ob + (size_t)(q0B + ln) * Dd + nd * 16 + quad * 4) = wv;
  }
}

}  // namespace

extern "C" void kernel_launch(void* const* d_in, const int* in_sizes, int n_in,
                              void* d_out, int out_size, void* d_ws, size_t ws_size,
                              hipStream_t stream) {
  const float* Q   = (const float*)d_in[0];
  const float* K   = (const float*)d_in[1];
  const float* V   = (const float*)d_in[2];
  const int*  mask = (const int*)d_in[3];
  float* Out = (float*)d_out;

  preprocess3<<<dim3(32, 32, 2), 256, 0, stream>>>(K, V, mask, (uint8_t*)d_ws);
  attn_fused6<<<dim3(Bb * Hh, Ss / 128), 256, 0, stream>>>(Q, (const uint8_t*)d_ws, Out);
  (void)ws_size; (void)in_sizes; (void)n_in; (void)out_size;
}